// Round 5
// baseline (245.960 us; speedup 1.0000x reference)
//
#include <hip/hip_runtime.h>

// Problem constants (from reference):
//   B=16, LX=2048, LR=1024, D=768, T = LX+LR+3 = 3075
// out[b,t,:] =
//   t==0                       -> CLS
//   1 <= t <= lx[b]            -> X[b, t-1, :]
//   t == lx[b]+1               -> RING
//   lx[b]+2 <= t < lx[b]+2+lr  -> Xr[b, t-lx[b]-2, :]
//   t == lx[b]+lr[b]+2         -> END
//   else                       -> 0
//
// R5: 192-thread blocks, 4 rows per block. Thread i handles float4 i of each
// of 4 consecutive rows -> 4 independent nontemporal loads in flight, then
// 4 nontemporal stores. 4x fewer waves/workgroups than R4; same byte counts.
// Rows within a block may straddle a batch boundary, so (b,t,lx,lr) are
// computed per row (cheap, L1-cached scalar-ish loads).

constexpr int B_  = 16;
constexpr int LX_ = 2048;
constexpr int LR_ = 1024;
constexpr int D_  = 768;
constexpr int T_  = LX_ + LR_ + 3;      // 3075
constexpr int NROW = B_ * T_;           // 49200 rows
constexpr int RPB  = 4;                 // rows per block (NROW % RPB == 0)

typedef float vfloat4 __attribute__((ext_vector_type(4)));

__global__ __launch_bounds__(192)
void assemble_row_kernel(const float* __restrict__ X,
                         const float* __restrict__ Xr,
                         const float* __restrict__ CLS,
                         const float* __restrict__ RING,
                         const float* __restrict__ END,
                         const int* __restrict__ lx,
                         const int* __restrict__ lr,
                         float* __restrict__ out)
{
    const unsigned row0 = blockIdx.x * RPB;
    const int doff = threadIdx.x * 4;         // float offset within a row

    vfloat4 val[RPB];

    #pragma unroll
    for (int r = 0; r < RPB; ++r) {
        const unsigned row = row0 + r;
        const unsigned b   = row / (unsigned)T_;   // magic-mul
        const int      t   = (int)(row - b * (unsigned)T_);
        const int lxb = lx[b];
        const int lrb = lr[b];

        val[r] = (vfloat4)(0.f);
        if (t == 0) {
            val[r] = *reinterpret_cast<const vfloat4*>(CLS + doff);
        } else if (t <= lxb) {
            const float* src = X + ((size_t)(b * LX_ + (t - 1)) * D_ + doff);
            val[r] = __builtin_nontemporal_load(reinterpret_cast<const vfloat4*>(src));
        } else if (t == lxb + 1) {
            val[r] = *reinterpret_cast<const vfloat4*>(RING + doff);
        } else if (t < lxb + 2 + lrb) {
            const float* src = Xr + ((size_t)(b * LR_ + (t - lxb - 2)) * D_ + doff);
            val[r] = __builtin_nontemporal_load(reinterpret_cast<const vfloat4*>(src));
        } else if (t == lxb + lrb + 2) {
            val[r] = *reinterpret_cast<const vfloat4*>(END + doff);
        }
    }

    #pragma unroll
    for (int r = 0; r < RPB; ++r) {
        const unsigned row = row0 + r;
        __builtin_nontemporal_store(val[r],
            reinterpret_cast<vfloat4*>(out + (size_t)row * D_ + doff));
    }
}

extern "C" void kernel_launch(void* const* d_in, const int* in_sizes, int n_in,
                              void* d_out, int out_size, void* d_ws, size_t ws_size,
                              hipStream_t stream)
{
    const float* X    = (const float*)d_in[0];
    const float* Xr   = (const float*)d_in[1];
    const float* CLS  = (const float*)d_in[2];
    const float* RING = (const float*)d_in[3];
    const float* END  = (const float*)d_in[4];
    const int* lx = (const int*)d_in[5];
    const int* lr = (const int*)d_in[6];
    float* out = (float*)d_out;

    hipLaunchKernelGGL(assemble_row_kernel, dim3(NROW / RPB), dim3(192), 0, stream,
                       X, Xr, CLS, RING, END, lx, lr, out);
}